// Round 4
// baseline (267.661 us; speedup 1.0000x reference)
//
#include <hip/hip_runtime.h>

// DiagLRConv: out[n,o,h,w] = sum_{k=0..4} sum_{i=0..15} fw[o,i,k] * x[n,i,h+k-2,w+k-2]
// x: (16,16,512,512) fp32, fw: (16,16,5) fp32, out: (16,16,512,512) fp32.

#define HH    512
#define WW    512
#define CH    16
#define KK    5
#define IMG   (HH * WW)     // 262144
#define CHIMG (CH * IMG)

typedef float f4 __attribute__((ext_vector_type(4)));
typedef f4 __attribute__((aligned(4))) f4u;   // 4B-aligned vector load (shifted)

// Zero row for out-of-range h taps: stride-0 channel trick reads [q, q+3], q<=508.
__device__ __attribute__((aligned(16))) float zrow_g[512];

// Load one channel-chunk (4 channels x 4 px) from row base RB with channel
// stride ST (0 for the zero row) at lane offset Q.
#define LOAD4(X0, X1, X2, X3, RB, ST, Q, C)                                   \
    X0 = *(const f4u*)((RB) + (size_t)(4 * (C) + 0) * (ST) + (Q));            \
    X1 = *(const f4u*)((RB) + (size_t)(4 * (C) + 1) * (ST) + (Q));            \
    X2 = *(const f4u*)((RB) + (size_t)(4 * (C) + 2) * (ST) + (Q));            \
    X3 = *(const f4u*)((RB) + (size_t)(4 * (C) + 3) * (ST) + (Q));

// FMA one chunk into acc: 16 o x 4 i x 4 px = 256 fmaf, weights broadcast b128.
#define FMA4(KU, C, X0, X1, X2, X3)                                           \
    {                                                                         \
        _Pragma("unroll")                                                     \
        for (int o = 0; o < CH; ++o) {                                        \
            f4 wq = *(const f4*)&Wlds[KU][o][4 * (C)];                        \
            acc[o].x = fmaf(wq.x, (X0).x, acc[o].x);                          \
            acc[o].y = fmaf(wq.x, (X0).y, acc[o].y);                          \
            acc[o].z = fmaf(wq.x, (X0).z, acc[o].z);                          \
            acc[o].w = fmaf(wq.x, (X0).w, acc[o].w);                          \
            acc[o].x = fmaf(wq.y, (X1).x, acc[o].x);                          \
            acc[o].y = fmaf(wq.y, (X1).y, acc[o].y);                          \
            acc[o].z = fmaf(wq.y, (X1).z, acc[o].z);                          \
            acc[o].w = fmaf(wq.y, (X1).w, acc[o].w);                          \
            acc[o].x = fmaf(wq.z, (X2).x, acc[o].x);                          \
            acc[o].y = fmaf(wq.z, (X2).y, acc[o].y);                          \
            acc[o].z = fmaf(wq.z, (X2).z, acc[o].z);                          \
            acc[o].w = fmaf(wq.z, (X2).w, acc[o].w);                          \
            acc[o].x = fmaf(wq.w, (X3).x, acc[o].x);                          \
            acc[o].y = fmaf(wq.w, (X3).y, acc[o].y);                          \
            acc[o].z = fmaf(wq.w, (X3).z, acc[o].z);                          \
            acc[o].w = fmaf(wq.w, (X3).w, acc[o].w);                          \
        }                                                                     \
    }

// ---------------- main kernel: interior (clamped w borders, fixed up later) -
// NOTE (round 2): __launch_bounds__(256,4) capped VGPR at 64 -> acc spilled ->
// 2.7 GB scratch traffic. Leave the allocator free.
__global__ __launch_bounds__(256)
void diag_conv_main(const float* __restrict__ x,
                    const float* __restrict__ fw,
                    float* __restrict__ out)
{
    __shared__ __align__(16) float Wlds[KK][CH][CH];   // [k][o][i]
    const int tid = threadIdx.x;
    for (int idx = tid; idx < KK * CH * CH; idx += 256) {
        int k   = idx >> 8;
        int rem = idx & 255;
        int o   = rem >> 4;
        int i   = rem & 15;
        Wlds[k][o][i] = fw[(o * CH + i) * KK + k];
    }
    __syncthreads();

    // Bijective XCD swizzle over 4096 blocks (8 XCDs x 512 contiguous ids).
    const int bid = blockIdx.x;
    const int swz = ((bid & 7) << 9) | (bid >> 3);
    const int wt  = swz & 1;          // w tile (0..1)
    const int ht  = (swz >> 1) & 127; // h tile (0..127)
    const int n   = swz >> 8;         // image (0..15)

    const int wave = __builtin_amdgcn_readfirstlane(tid >> 6);
    const int lane = tid & 63;
    const int h    = ht * 4 + wave;          // wave-uniform
    const int w0   = wt * 256 + lane * 4;    // 4 contiguous px per lane

    const float* __restrict__ xn = x + (size_t)n * CHIMG;

    f4 acc[CH];
#pragma unroll
    for (int o = 0; o < CH; ++o) acc[o] = (f4){0.f, 0.f, 0.f, 0.f};

    // ---- current-k row state (k = 0) ----
    const float* rbc;
    size_t stc;
    int qc;
    {
        const int hh = h - 2;
        const bool v = (unsigned)hh < (unsigned)HH;
        rbc = v ? xn + (size_t)hh * WW : zrow_g;
        stc = v ? (size_t)IMG : 0;
        int t = w0 - 2;
        qc = t < 0 ? 0 : (t > WW - 4 ? WW - 4 : t);
    }

    f4 a0, a1, a2, a3, b0, b1, b2, b3;
    LOAD4(a0, a1, a2, a3, rbc, stc, qc, 0);   // chunk (k=0, c=0)
    LOAD4(b0, b1, b2, b3, rbc, stc, qc, 1);   // chunk (k=0, c=1)

#pragma unroll 1
    for (int k = 0; k < KK; ++k) {
        // Prep next-k row (k+1); k+1 == KK or invalid h -> zero row.
        const int hn   = h + k - 1;             // (k+1) - 2
        const bool vn  = ((unsigned)hn < (unsigned)HH) & (k + 1 < KK);
        const float* rbn = vn ? xn + (size_t)hn * WW : zrow_g;
        const size_t stn = vn ? (size_t)IMG : 0;
        int tn = w0 + k - 1;
        const int qn = tn < 0 ? 0 : (tn > WW - 4 ? WW - 4 : tn);

        // Chunk-pipelined: FMA(q) ; LOAD(q+2).  20-chunk stream, depth 2.
        FMA4(k, 0, a0, a1, a2, a3);
        LOAD4(a0, a1, a2, a3, rbc, stc, qc, 2);
        FMA4(k, 1, b0, b1, b2, b3);
        LOAD4(b0, b1, b2, b3, rbc, stc, qc, 3);
        FMA4(k, 2, a0, a1, a2, a3);
        LOAD4(a0, a1, a2, a3, rbn, stn, qn, 0);
        FMA4(k, 3, b0, b1, b2, b3);
        LOAD4(b0, b1, b2, b3, rbn, stn, qn, 1);

        rbc = rbn; stc = stn; qc = qn;
    }

    float* __restrict__ on = out + (size_t)n * CHIMG + (size_t)h * WW + w0;
#pragma unroll
    for (int o = 0; o < CH; ++o)
        *(f4*)(on + (size_t)o * IMG) = acc[o];   // 16B aligned
}

// ---------------- fixup kernel: recompute w in {0..3, 508..511} exactly -----
__global__ __launch_bounds__(256)
void diag_conv_fixup(const float* __restrict__ x,
                     const float* __restrict__ fw,
                     float* __restrict__ out)
{
    __shared__ __align__(16) float Wl[KK][CH][CH];   // [k][i][o]
    const int tid = threadIdx.x;
    for (int idx = tid; idx < KK * CH * CH; idx += 256) {
        int k   = idx >> 8;
        int rem = idx & 255;
        int i   = rem >> 4;
        int o   = rem & 15;
        Wl[k][i][o] = fw[(o * CH + i) * KK + k];
    }
    __syncthreads();

    const int wi = tid & 7;
    const int w  = wi < 4 ? wi : (WW - 8 + wi);          // 0..3 or 508..511
    const int h  = blockIdx.x * 32 + (tid >> 3);         // 32 h rows per block
    const int n  = blockIdx.y;

    f4 acc4[4];
#pragma unroll
    for (int u = 0; u < 4; ++u) acc4[u] = (f4){0.f, 0.f, 0.f, 0.f};

#pragma unroll
    for (int k = 0; k < KK; ++k) {
        const int hh = h + k - 2;
        const int ww = w + k - 2;
        if ((unsigned)hh >= (unsigned)HH || (unsigned)ww >= (unsigned)WW) continue;
        const float* __restrict__ xp = x + (size_t)n * CHIMG + (size_t)hh * WW + ww;
#pragma unroll
        for (int i = 0; i < CH; ++i) {
            const float xi = xp[(size_t)i * IMG];
#pragma unroll
            for (int u = 0; u < 4; ++u) {
                f4 w4 = *(const f4*)&Wl[k][i][4 * u];
                acc4[u].x = fmaf(w4.x, xi, acc4[u].x);
                acc4[u].y = fmaf(w4.y, xi, acc4[u].y);
                acc4[u].z = fmaf(w4.z, xi, acc4[u].z);
                acc4[u].w = fmaf(w4.w, xi, acc4[u].w);
            }
        }
    }

#pragma unroll
    for (int u = 0; u < 4; ++u) {
        out[(size_t)(n * CH + 4 * u + 0) * IMG + (size_t)h * WW + w] = acc4[u].x;
        out[(size_t)(n * CH + 4 * u + 1) * IMG + (size_t)h * WW + w] = acc4[u].y;
        out[(size_t)(n * CH + 4 * u + 2) * IMG + (size_t)h * WW + w] = acc4[u].z;
        out[(size_t)(n * CH + 4 * u + 3) * IMG + (size_t)h * WW + w] = acc4[u].w;
    }
}

extern "C" void kernel_launch(void* const* d_in, const int* in_sizes, int n_in,
                              void* d_out, int out_size, void* d_ws, size_t ws_size,
                              hipStream_t stream)
{
    const float* x  = (const float*)d_in[0];
    const float* fw = (const float*)d_in[1];
    float* out      = (float*)d_out;

    diag_conv_main<<<dim3(4096), dim3(256), 0, stream>>>(x, fw, out);
    diag_conv_fixup<<<dim3(HH / 32, 16), dim3(256), 0, stream>>>(x, fw, out);
}

// Round 5
// 157.030 us; speedup vs baseline: 1.7045x; 1.7045x over previous
//
#include <hip/hip_runtime.h>

// DiagLRConv via bf16 MFMA: out[n,o,h,w] = sum_{k,i} fw[o,i,k] * x[n,i,h+k-2,w+k-2]
// x: (16,16,512,512) fp32, fw: (16,16,5) fp32, out fp32.
// GEMM view per tile: out(o,px) = sum_K W'(o,K) X'(px,K), K=(tap,i) padded 80->96,
// 3x mfma_f32_16x16x32_bf16 per 16x16 tile, fp32 accumulate.

#define HH    512
#define WW    512
#define CH    16
#define KK    5
#define IMG   (HH * WW)
#define CHIMG (CH * IMG)

#define HT 16            // output rows per block
#define WT 64            // output px per block
#define RI 20            // staged input rows  (HT + 4 halo)
#define WI 68            // staged input px    (WT + 4 halo)
#define NCHUNK (RI * 2)  // (row, channel-half) chunks

typedef __attribute__((ext_vector_type(8))) short bf16x8;
typedef __attribute__((ext_vector_type(4))) float f32x4;
typedef __attribute__((ext_vector_type(4))) int   i32x4;

union I4S8 { i32x4 i; bf16x8 s; };

// pack two f32 -> two bf16 (RNE): D[15:0]=bf16(lo), D[31:16]=bf16(hi)
__device__ __forceinline__ unsigned cvt_pk_bf16(float lo, float hi) {
    unsigned r;
    asm("v_cvt_pk_bf16_f32 %0, %1, %2" : "=v"(r) : "v"(lo), "v"(hi));
    return r;
}

__global__ __launch_bounds__(256)
void diag_conv_mfma(const float* __restrict__ x,
                    const float* __restrict__ fw,
                    float* __restrict__ out)
{
    // LDS tile: [chunk = ri*2 + ch_half][wi] -> int4 = 8 bf16 (channels ih*8..ih*8+7)
    // 16B units: ds_read/write_b128; within a 16-lane quarter addresses stride 16B
    // -> 8 banks x 2-way = conflict-free (m136: 2-way is free).
    __shared__ i32x4 xl[NCHUNK * WI];   // 40*68*16B = 43.5 KB -> 3 blocks/CU

    const int tid = threadIdx.x;

    // Bijective XCD swizzle over 4096 blocks (8 XCDs x 512 contiguous ids):
    // one XCD gets 2 images' worth of contiguous (ht, wt) tiles -> halo L2 hits.
    const int bid = blockIdx.x;
    const int swz = ((bid & 7) << 9) | (bid >> 3);
    const int n  = swz >> 8;          // 0..15
    const int ht = (swz >> 3) & 31;   // 0..31
    const int wt = swz & 7;           // 0..7
    const int h0 = ht * HT;
    const int w0 = wt * WT;

    const int wv   = tid >> 6;        // wave 0..3
    const int lane = tid & 63;

    const float* __restrict__ xn = x + (size_t)n * CHIMG;

    // ---------------- stage x -> LDS (bf16, zero-padded borders) ------------
    // main: wi = lane (0..63); units (ri, ih) round-robin across waves
#pragma unroll
    for (int u = 0; u < 10; ++u) {
        const int unit = u * 4 + wv;          // 0..39
        const int ri = unit >> 1;
        const int ih = unit & 1;
        const int r  = h0 - 2 + ri;
        const int w  = w0 - 2 + lane;
        const bool ok = ((unsigned)r < (unsigned)HH) & ((unsigned)w < (unsigned)WW);
        const int rc = r < 0 ? 0 : (r > HH - 1 ? HH - 1 : r);
        const int wc = w < 0 ? 0 : (w > WW - 1 ? WW - 1 : w);
        const float* __restrict__ p8 = xn + (size_t)(ih * 8) * IMG + (size_t)rc * WW + wc;
        float v0 = p8[0 * (size_t)IMG], v1 = p8[1 * (size_t)IMG];
        float v2 = p8[2 * (size_t)IMG], v3 = p8[3 * (size_t)IMG];
        float v4 = p8[4 * (size_t)IMG], v5 = p8[5 * (size_t)IMG];
        float v6 = p8[6 * (size_t)IMG], v7 = p8[7 * (size_t)IMG];
        if (!ok) { v0=v1=v2=v3=v4=v5=v6=v7 = 0.f; }
        i32x4 pk;
        pk.x = (int)cvt_pk_bf16(v0, v1);
        pk.y = (int)cvt_pk_bf16(v2, v3);
        pk.z = (int)cvt_pk_bf16(v4, v5);
        pk.w = (int)cvt_pk_bf16(v6, v7);
        xl[unit * WI + lane] = pk;
    }
    // tail: wi = 64..67 ; 160 threads cover (ri 0..19) x (wi 4) x (ih 2)
    if (tid < 160) {
        const int ri  = tid >> 3;
        const int rem = tid & 7;
        const int wi  = 64 + (rem & 3);
        const int ih  = rem >> 2;
        const int r   = h0 - 2 + ri;
        const int w   = w0 - 2 + wi;
        const bool ok = ((unsigned)r < (unsigned)HH) & ((unsigned)w < (unsigned)WW);
        const int rc = r < 0 ? 0 : (r > HH - 1 ? HH - 1 : r);
        const int wc = w < 0 ? 0 : (w > WW - 1 ? WW - 1 : w);
        const float* __restrict__ p8 = xn + (size_t)(ih * 8) * IMG + (size_t)rc * WW + wc;
        float v0 = p8[0 * (size_t)IMG], v1 = p8[1 * (size_t)IMG];
        float v2 = p8[2 * (size_t)IMG], v3 = p8[3 * (size_t)IMG];
        float v4 = p8[4 * (size_t)IMG], v5 = p8[5 * (size_t)IMG];
        float v6 = p8[6 * (size_t)IMG], v7 = p8[7 * (size_t)IMG];
        if (!ok) { v0=v1=v2=v3=v4=v5=v6=v7 = 0.f; }
        i32x4 pk;
        pk.x = (int)cvt_pk_bf16(v0, v1);
        pk.y = (int)cvt_pk_bf16(v2, v3);
        pk.z = (int)cvt_pk_bf16(v4, v5);
        pk.w = (int)cvt_pk_bf16(v6, v7);
        xl[(ri * 2 + ih) * WI + wi] = pk;
    }

    // ---------------- A fragments (weights, bf16) ---------------------------
    // mfma_f32_16x16x32_bf16: D(m=o, n=px) = sum_K A(m,K) B(n,K).
    // Lane l: m(or n) = l&15 ; K-slot = (l>>4)*8 + j  ->  tap = 2s + (l>>5),
    // i = ((l>>4)&1)*8 + j.  s=2 pairs taps {4, pad}; pad lanes get A=0.
    const int p   = lane & 15;
    const int ihl = (lane >> 4) & 1;
    const int tb  = lane >> 5;

    bf16x8 afrag[3];
#pragma unroll
    for (int s = 0; s < 3; ++s) {
        const int tap = 2 * s + tb;
        I4S8 a;
        a.i = (i32x4){0, 0, 0, 0};
        if (tap < KK) {
            const float* __restrict__ wp = fw + ((size_t)p * CH + ihl * 8) * KK + tap;
            float q0 = wp[0 * KK], q1 = wp[1 * KK], q2 = wp[2 * KK], q3 = wp[3 * KK];
            float q4 = wp[4 * KK], q5 = wp[5 * KK], q6 = wp[6 * KK], q7 = wp[7 * KK];
            a.i.x = (int)cvt_pk_bf16(q0, q1);
            a.i.y = (int)cvt_pk_bf16(q2, q3);
            a.i.z = (int)cvt_pk_bf16(q4, q5);
            a.i.w = (int)cvt_pk_bf16(q6, q7);
        }
        afrag[s] = a.s;
    }

    __syncthreads();

    // ---------------- MFMA: 4 rows x 4 px-groups x 3 K-slices ---------------
    f32x4 acc[4][4];
#pragma unroll
    for (int yy = 0; yy < 4; ++yy)
#pragma unroll
        for (int g = 0; g < 4; ++g) acc[yy][g] = (f32x4){0.f, 0.f, 0.f, 0.f};

    const int ybase = wv * 4;
#pragma unroll
    for (int yy = 0; yy < 4; ++yy) {
#pragma unroll
        for (int s = 0; s < 3; ++s) {
            const int tap = 2 * s + tb;                  // per-lane
            int ri = ybase + yy + tap;                   // staged row index
            ri = ri > RI - 1 ? RI - 1 : ri;              // clamp pad-tap lanes (A=0)
            const int c = ri * 2 + ihl;
#pragma unroll
            for (int g = 0; g < 4; ++g) {
                int wi = g * 16 + p + tap;
                wi = wi > WI - 1 ? WI - 1 : wi;          // clamp pad-tap lanes
                I4S8 b;
                b.i = xl[c * WI + wi];                   // ds_read_b128
                acc[yy][g] = __builtin_amdgcn_mfma_f32_16x16x32_bf16(
                    afrag[s], b.s, acc[yy][g], 0, 0, 0);
            }
        }
    }

    // ---------------- store: D col = lane&15 = px, row = (lane>>4)*4+reg = o -
    float* __restrict__ on = out + (size_t)n * CHIMG;
    const int og = (lane >> 4) << 2;
#pragma unroll
    for (int yy = 0; yy < 4; ++yy) {
        const int h = h0 + ybase + yy;
#pragma unroll
        for (int g = 0; g < 4; ++g) {
            const int wbase = w0 + g * 16 + p;
#pragma unroll
            for (int reg = 0; reg < 4; ++reg) {
                const int o = og + reg;
                on[(size_t)o * IMG + (size_t)h * WW + wbase] = acc[yy][g][reg];
            }
        }
    }
}

extern "C" void kernel_launch(void* const* d_in, const int* in_sizes, int n_in,
                              void* d_out, int out_size, void* d_ws, size_t ws_size,
                              hipStream_t stream)
{
    const float* x  = (const float*)d_in[0];
    const float* fw = (const float*)d_in[1];
    float* out      = (float*)d_out;

    // 4096 blocks = 16 n x 32 ht x 8 wt
    diag_conv_mfma<<<dim3(4096), dim3(256), 0, stream>>>(x, fw, out);
}